// Round 2
// baseline (424.824 us; speedup 1.0000x reference)
//
#include <hip/hip_runtime.h>
#include <cstdint>

#define NA_N 50000
#define NB_N 50000
#define NE_N 800000
#define DD 256

// ---------------- GEMM: C[NB,256] = A[NB,256] @ W[256,256] + bias ----------------
// BM=16 rows/block, full K=256, full N=256 (thread t owns column t).
// A tile staged in LDS (16 KB); W streamed from global (L2-resident, read once per block).
__global__ __launch_bounds__(256) void gemm16(const float* __restrict__ A,
    const float* __restrict__ W, const float* __restrict__ bias,
    float* __restrict__ C)
{
    __shared__ float As[16 * DD];
    const int t  = threadIdx.x;
    const int r0 = blockIdx.x * 16;

    const float4* Ag  = (const float4*)(A + (size_t)r0 * DD);
    float4*       Asv = (float4*)As;
#pragma unroll
    for (int i = 0; i < 4; i++) Asv[i * 256 + t] = Ag[i * 256 + t];
    __syncthreads();

    float acc[16];
#pragma unroll
    for (int m = 0; m < 16; m++) acc[m] = 0.f;

    const float* Wc = W + t;
    for (int k = 0; k < DD; k += 4) {
        float w0 = Wc[(k + 0) * DD];
        float w1 = Wc[(k + 1) * DD];
        float w2 = Wc[(k + 2) * DD];
        float w3 = Wc[(k + 3) * DD];
#pragma unroll
        for (int m = 0; m < 16; m++) {
            float4 av = *(const float4*)&As[m * DD + k];   // broadcast ds_read_b128
            acc[m] = fmaf(av.x, w0, acc[m]);
            acc[m] = fmaf(av.y, w1, acc[m]);
            acc[m] = fmaf(av.z, w2, acc[m]);
            acc[m] = fmaf(av.w, w3, acc[m]);
        }
    }

    float bv = bias[t];
#pragma unroll
    for (int m = 0; m < 16; m++)
        C[(size_t)(r0 + m) * DD + t] = acc[m] + bv;
}

// ---------------- row-dot: out[i] = dot(M[i,:256], v[:256]) ----------------
// one wave per row, float4 per lane (64*4 = 256), shuffle reduce.
__global__ __launch_bounds__(256) void rowdot(const float* __restrict__ M,
    const float* __restrict__ v, float* __restrict__ out, int nrows)
{
    const int lane = threadIdx.x & 63;
    const int wave = threadIdx.x >> 6;
    const int row  = blockIdx.x * 4 + wave;
    if (row >= nrows) return;

    float4 av = ((const float4*)(M + (size_t)row * DD))[lane];
    float4 bv = ((const float4*)v)[lane];
    float  s  = av.x * bv.x + av.y * bv.y + av.z * bv.z + av.w * bv.w;
#pragma unroll
    for (int off = 32; off; off >>= 1) s += __shfl_down(s, off, 64);
    if (lane == 0) out[row] = s;
}

// ---------------- edge aggregation ----------------
// 256 edges/block. Phase 1: per-edge score into LDS. Phase 2: each wave walks a
// contiguous 64-edge sub-chunk; lane holds float4 (4 columns); segment
// accumulation in registers (edge_src is sorted), atomicAdd flush on src change.
__global__ __launch_bounds__(256) void edge_agg(
    const int* __restrict__ esrc, const int* __restrict__ edst,
    const float* __restrict__ sa, const float* __restrict__ sb,
    const float* __restrict__ emb, float* __restrict__ out,
    float* __restrict__ rowsum, int ne)
{
    __shared__ int   s_src[256];
    __shared__ int   s_dst[256];
    __shared__ float s_sc[256];

    const int t    = threadIdx.x;
    const int base = blockIdx.x * 256;
    const int n    = min(256, ne - base);

    if (t < n) {
        int   src = esrc[base + t];
        int   dst = edst[base + t];
        float lg  = sa[src] + sb[dst];
        float el  = lg > 0.f ? lg : 0.1f * expm1f(lg);
        s_src[t] = src;
        s_dst[t] = dst;
        s_sc[t]  = expf(el);
    }
    __syncthreads();

    const int lane = t & 63;
    const int wave = t >> 6;
    const int e0   = wave * 64;
    const int e1   = min(n, e0 + 64);

    float4 acc  = {0.f, 0.f, 0.f, 0.f};
    float  asum = 0.f;
    int    cur  = -1;

    for (int e = e0; e < e1; e++) {
        int src = s_src[e];
        if (src != cur) {                      // wave-uniform branch (all lanes same e)
            if (cur >= 0) {
                float* o = out + (size_t)cur * DD + lane * 4;
                atomicAdd(o + 0, acc.x);
                atomicAdd(o + 1, acc.y);
                atomicAdd(o + 2, acc.z);
                atomicAdd(o + 3, acc.w);
                if (lane == 0) atomicAdd(&rowsum[cur], asum);
            }
            cur  = src;
            acc  = {0.f, 0.f, 0.f, 0.f};
            asum = 0.f;
        }
        float  sc = s_sc[e];
        float4 ev = ((const float4*)(emb + (size_t)s_dst[e] * DD))[lane];
        acc.x = fmaf(sc, ev.x, acc.x);
        acc.y = fmaf(sc, ev.y, acc.y);
        acc.z = fmaf(sc, ev.z, acc.z);
        acc.w = fmaf(sc, ev.w, acc.w);
        asum += sc;
    }
    if (cur >= 0) {
        float* o = out + (size_t)cur * DD + lane * 4;
        atomicAdd(o + 0, acc.x);
        atomicAdd(o + 1, acc.y);
        atomicAdd(o + 2, acc.z);
        atomicAdd(o + 3, acc.w);
        if (lane == 0) atomicAdd(&rowsum[cur], asum);
    }
}

// ---------------- normalize: out[i,:] /= max(rowsum[i], !=0) ----------------
__global__ __launch_bounds__(256) void norm_k(float* __restrict__ out,
    const float* __restrict__ rowsum, int nrows)
{
    const int lane = threadIdx.x & 63;
    const int wave = threadIdx.x >> 6;
    const int row  = blockIdx.x * 4 + wave;
    if (row >= nrows) return;

    float rs  = rowsum[row];
    float inv = (rs == 0.f) ? 1.f : (1.f / rs);

    float4* p = (float4*)(out + (size_t)row * DD);
    float4  v = p[lane];
    v.x *= inv; v.y *= inv; v.z *= inv; v.w *= inv;
    p[lane] = v;
}

extern "C" void kernel_launch(void* const* d_in, const int* in_sizes, int n_in,
                              void* d_out, int out_size, void* d_ws, size_t ws_size,
                              hipStream_t stream)
{
    const float* fa   = (const float*)d_in[0];
    const float* fb   = (const float*)d_in[1];
    const float* W    = (const float*)d_in[2];
    const float* bias = (const float*)d_in[3];
    const float* avec = (const float*)d_in[4];
    const int*   esrc = (const int*)d_in[5];   // harness passes integers as int32
    const int*   edst = (const int*)d_in[6];
    float*       out  = (float*)d_out;

    char*  ws      = (char*)d_ws;
    float* new_emb = (float*)ws;                              // NB*256 fp32 = 51.2 MB
    float* s_a     = (float*)(ws + (size_t)NB_N * DD * 4);    // NA
    float* s_b     = s_a + NA_N;                              // NB
    float* rowsum  = s_b + NB_N;                              // NA

    hipMemsetAsync(d_out, 0, (size_t)NA_N * DD * sizeof(float), stream);
    hipMemsetAsync(rowsum, 0, (size_t)NA_N * sizeof(float), stream);

    gemm16<<<NB_N / 16, 256, 0, stream>>>(fb, W, bias, new_emb);
    rowdot<<<(NA_N + 3) / 4, 256, 0, stream>>>(fa, avec, s_a, NA_N);
    rowdot<<<(NB_N + 3) / 4, 256, 0, stream>>>(new_emb, avec + DD, s_b, NB_N);
    edge_agg<<<(NE_N + 255) / 256, 256, 0, stream>>>(esrc, edst, s_a, s_b,
                                                     new_emb, out, rowsum, NE_N);
    norm_k<<<(NA_N + 3) / 4, 256, 0, stream>>>(out, rowsum, NA_N);
}

// Round 3
// 133.382 us; speedup vs baseline: 3.1850x; 3.1850x over previous
//
#include <hip/hip_runtime.h>
#include <cstdint>

#define NA_N 50000
#define NB_N 50000
#define NE_N 800000
#define DD 256

using bf8   = __attribute__((ext_vector_type(8))) short;   // 8 bf16 = 4 VGPR
using f32x4 = __attribute__((ext_vector_type(4))) float;

__device__ __forceinline__ ushort f2bf(float f) {
    uint u = __float_as_uint(f);
    uint r = (u + 0x7fffu + ((u >> 16) & 1u)) >> 16;       // RNE
    return (ushort)r;
}
__device__ __forceinline__ float bf2f(ushort u) {
    return __uint_as_float(((uint)u) << 16);
}

// ---------------- W transpose+cast: Wt[n][k] = bf16(W[k][n]) ----------------
__global__ __launch_bounds__(256) void wt_cast(const float* __restrict__ W,
                                               ushort* __restrict__ Wt)
{
    __shared__ float T[64][65];
    const int bi = blockIdx.x & 3;        // k tile
    const int bj = blockIdx.x >> 2;       // n tile
    const int lane = threadIdx.x & 63, w = threadIdx.x >> 6;
    for (int i = w; i < 64; i += 4)
        T[i][lane] = W[(size_t)(bi * 64 + i) * DD + bj * 64 + lane];
    __syncthreads();
    for (int i = w; i < 64; i += 4)
        Wt[(size_t)(bj * 64 + i) * DD + bi * 64 + lane] = f2bf(T[lane][i]);
}

// ---------------- GEMM: emb_b[NB,256](bf16) = bf16(fb) @ W + bias ----------------
// 256 thr = 4 waves. BM=64, BN=256 (wave owns 64-col strip). A staged fp32->bf16
// in LDS (stride 264 to break bank conflicts); B-frags read straight from Wt
// (L2-resident, lane reads 8 contiguous k for its col — B^T pattern, m92).
__global__ __launch_bounds__(256) void gemm_mfma(
    const float* __restrict__ A, const ushort* __restrict__ Wt,
    const float* __restrict__ bias, ushort* __restrict__ C)
{
    __shared__ ushort As[64 * 264];
    const int t  = threadIdx.x;
    const int r0 = blockIdx.x * 64;

#pragma unroll
    for (int i = 0; i < 16; i++) {
        int flat = i * 256 + t;            // float4 index within 64x64 f4 tile
        int row  = flat >> 6;
        int c4   = flat & 63;
        int gr   = r0 + row; if (gr >= NB_N) gr = 0;      // clamp tail
        float4 v = ((const float4*)(A + (size_t)gr * DD))[c4];
        ushort4 b;
        b.x = f2bf(v.x); b.y = f2bf(v.y); b.z = f2bf(v.z); b.w = f2bf(v.w);
        *(ushort4*)&As[row * 264 + c4 * 4] = b;
    }
    __syncthreads();

    const int lane = t & 63;
    const int wv   = t >> 6;
    const int lr   = lane & 15;
    const int lk   = (lane >> 4) * 8;

    f32x4 acc[4][4];
#pragma unroll
    for (int m = 0; m < 4; m++)
#pragma unroll
        for (int n = 0; n < 4; n++) acc[m][n] = (f32x4){0.f, 0.f, 0.f, 0.f};

#pragma unroll
    for (int ks = 0; ks < 8; ks++) {
        const int k0 = ks * 32;
        bf8 af[4], bb[4];
#pragma unroll
        for (int m = 0; m < 4; m++)
            af[m] = *(const bf8*)&As[(m * 16 + lr) * 264 + k0 + lk];
#pragma unroll
        for (int n = 0; n < 4; n++) {
            int col = wv * 64 + n * 16 + lr;
            bb[n] = *(const bf8*)&Wt[(size_t)col * DD + k0 + lk];
        }
#pragma unroll
        for (int m = 0; m < 4; m++)
#pragma unroll
            for (int n = 0; n < 4; n++)
                acc[m][n] = __builtin_amdgcn_mfma_f32_16x16x32_bf16(
                    af[m], bb[n], acc[m][n], 0, 0, 0);
    }

#pragma unroll
    for (int m = 0; m < 4; m++)
#pragma unroll
        for (int n = 0; n < 4; n++) {
            int col = wv * 64 + n * 16 + lr;
            float bv = bias[col];
#pragma unroll
            for (int r = 0; r < 4; r++) {
                int rowg = r0 + m * 16 + (lane >> 4) * 4 + r;   // C: col=lane&15, row=(lane>>4)*4+r (m89)
                if (rowg < NB_N)
                    C[(size_t)rowg * DD + col] = f2bf(acc[m][n][r] + bv);
            }
        }
}

// ---------------- row-dot fp32: s_a[i] = dot(fa[i,:], a_top) ----------------
__global__ __launch_bounds__(256) void rowdot(const float* __restrict__ M,
    const float* __restrict__ v, float* __restrict__ out, int nrows)
{
    const int lane = threadIdx.x & 63;
    const int row  = blockIdx.x * 4 + (threadIdx.x >> 6);
    if (row >= nrows) return;
    float4 av = ((const float4*)(M + (size_t)row * DD))[lane];
    float4 bv = ((const float4*)v)[lane];
    float  s  = av.x * bv.x + av.y * bv.y + av.z * bv.z + av.w * bv.w;
#pragma unroll
    for (int off = 32; off; off >>= 1) s += __shfl_down(s, off, 64);
    if (lane == 0) out[row] = s;
}

// ---------------- row-dot bf16: s_b[i] = dot(emb_b[i,:], a_bot) ----------------
__global__ __launch_bounds__(256) void rowdot_bf(const ushort* __restrict__ M,
    const float* __restrict__ v, float* __restrict__ out, int nrows)
{
    const int lane = threadIdx.x & 63;
    const int row  = blockIdx.x * 4 + (threadIdx.x >> 6);
    if (row >= nrows) return;
    ushort4 u = ((const ushort4*)(M + (size_t)row * DD))[lane];
    float4 bv = ((const float4*)v)[lane];
    float  s  = bf2f(u.x) * bv.x + bf2f(u.y) * bv.y + bf2f(u.z) * bv.z + bf2f(u.w) * bv.w;
#pragma unroll
    for (int off = 32; off; off >>= 1) s += __shfl_down(s, off, 64);
    if (lane == 0) out[row] = s;
}

// ---------------- row_start[r] = first e with esrc[e] >= r (esrc sorted) ----------------
__global__ void rowstart_k(const int* __restrict__ esrc, int* __restrict__ row_start)
{
    int e = blockIdx.x * 256 + threadIdx.x;
    if (e >= NE_N) return;
    int s    = esrc[e];
    int prev = (e == 0) ? -1 : esrc[e - 1];
    for (int r = prev + 1; r <= s; r++) row_start[r] = e;
    if (e == NE_N - 1)
        for (int r = s + 1; r <= NA_N; r++) row_start[r] = NE_N;
}

// ---------------- edge aggregation: one wave per source row, no atomics ----------------
// Lanes 0..len-1 load dst + compute score in parallel; then the wave iterates
// edges via shfl broadcast, each lane gathering its 4 bf16 columns. Fused
// normalize + store (covers empty rows -> zeros).
__global__ __launch_bounds__(256) void edge_agg2(
    const int* __restrict__ edst, const int* __restrict__ row_start,
    const float* __restrict__ sa, const float* __restrict__ sb,
    const ushort* __restrict__ emb, float* __restrict__ out)
{
    const int lane = threadIdx.x & 63;
    const int a    = blockIdx.x * 4 + (threadIdx.x >> 6);
    if (a >= NA_N) return;

    const int beg = row_start[a], end = row_start[a + 1];
    const float sa_a = sa[a];

    float4 acc = {0.f, 0.f, 0.f, 0.f};
    float  rs  = 0.f;

    for (int base = beg; base < end; base += 64) {
        const int len = min(64, end - base);
        int   d  = 0;
        float sc = 0.f;
        if (lane < len) {
            d = edst[base + lane];
            float lg = sa_a + sb[d];
            float el = lg > 0.f ? lg : 0.1f * expm1f(lg);
            sc = expf(el);
        }
        for (int k = 0; k < len; k++) {
            float s  = __shfl(sc, k, 64);
            int   dd = __shfl(d, k, 64);
            ushort4 u = *(const ushort4*)(emb + (size_t)dd * DD + lane * 4);
            acc.x = fmaf(s, bf2f(u.x), acc.x);
            acc.y = fmaf(s, bf2f(u.y), acc.y);
            acc.z = fmaf(s, bf2f(u.z), acc.z);
            acc.w = fmaf(s, bf2f(u.w), acc.w);
            rs += s;
        }
    }

    const float inv = (rs == 0.f) ? 1.f : (1.f / rs);
    float4 o;
    o.x = acc.x * inv; o.y = acc.y * inv; o.z = acc.z * inv; o.w = acc.w * inv;
    *(float4*)(out + (size_t)a * DD + lane * 4) = o;
}

extern "C" void kernel_launch(void* const* d_in, const int* in_sizes, int n_in,
                              void* d_out, int out_size, void* d_ws, size_t ws_size,
                              hipStream_t stream)
{
    const float* fa   = (const float*)d_in[0];
    const float* fb   = (const float*)d_in[1];
    const float* W    = (const float*)d_in[2];
    const float* bias = (const float*)d_in[3];
    const float* avec = (const float*)d_in[4];
    const int*   esrc = (const int*)d_in[5];
    const int*   edst = (const int*)d_in[6];
    float*       out  = (float*)d_out;

    char*   ws        = (char*)d_ws;
    ushort* emb_b     = (ushort*)ws;                               // NB*256 bf16 = 25.6 MB
    float*  s_a       = (float*)(ws + (size_t)NB_N * DD * 2);      // NA
    float*  s_b       = s_a + NA_N;                                // NB
    int*    row_start = (int*)(s_b + NB_N);                        // NA+1
    ushort* Wt        = (ushort*)(row_start + NA_N + 1);           // 256*256 bf16

    wt_cast  <<<16, 256, 0, stream>>>(W, Wt);
    gemm_mfma<<<(NB_N + 63) / 64, 256, 0, stream>>>(fb, Wt, bias, emb_b);
    rowdot   <<<(NA_N + 3) / 4, 256, 0, stream>>>(fa, avec, s_a, NA_N);
    rowdot_bf<<<(NB_N + 3) / 4, 256, 0, stream>>>(emb_b, avec + DD, s_b, NB_N);
    rowstart_k<<<(NE_N + 255) / 256, 256, 0, stream>>>(esrc, row_start);
    edge_agg2<<<(NA_N + 3) / 4, 256, 0, stream>>>(edst, row_start, s_a, s_b,
                                                  emb_b, out);
}

// Round 4
// 126.657 us; speedup vs baseline: 3.3541x; 1.0531x over previous
//
#include <hip/hip_runtime.h>
#include <cstdint>

#define NA_N 50000
#define NB_N 50000
#define NE_N 800000
#define DD 256

using bf8   = __attribute__((ext_vector_type(8))) short;   // 8 bf16 = 4 VGPR
using f32x4 = __attribute__((ext_vector_type(4))) float;
using u16x8 = __attribute__((ext_vector_type(8))) ushort;

__device__ __forceinline__ ushort f2bf(float f) {
    uint u = __float_as_uint(f);
    uint r = (u + 0x7fffu + ((u >> 16) & 1u)) >> 16;       // RNE
    return (ushort)r;
}
__device__ __forceinline__ float bf2f(ushort u) {
    return __uint_as_float(((uint)u) << 16);
}

// ---------------- W transpose+cast: Wt[n][k] = bf16(W[k][n]) ----------------
__global__ __launch_bounds__(256) void wt_cast(const float* __restrict__ W,
                                               ushort* __restrict__ Wt)
{
    __shared__ float T[64][65];
    const int bi = blockIdx.x & 3;        // k tile
    const int bj = blockIdx.x >> 2;       // n tile
    const int lane = threadIdx.x & 63, w = threadIdx.x >> 6;
    for (int i = w; i < 64; i += 4)
        T[i][lane] = W[(size_t)(bi * 64 + i) * DD + bj * 64 + lane];
    __syncthreads();
    for (int i = w; i < 64; i += 4)
        Wt[(size_t)(bj * 64 + i) * DD + bi * 64 + lane] = f2bf(T[lane][i]);
}

// ------- GEMM: emb_b[NB,256](bf16) = bf16(fb) @ W + bias ; fused s_b = emb @ a_bot -------
// 256 thr = 4 waves. BM=64; wave owns a 64-col strip. A staged fp32->bf16 in LDS
// (stride 264 breaks bank conflicts); B frags straight from L2-resident Wt (B^T, m92).
__global__ __launch_bounds__(256) void gemm_mfma(
    const float* __restrict__ A, const ushort* __restrict__ Wt,
    const float* __restrict__ bias, const float* __restrict__ a_bot,
    ushort* __restrict__ C, float* __restrict__ s_b)
{
    __shared__ ushort As[64 * 264];
    __shared__ float  sdot[4][64];
    const int t  = threadIdx.x;
    const int r0 = blockIdx.x * 64;

#pragma unroll
    for (int i = 0; i < 16; i++) {
        int flat = i * 256 + t;            // float4 index within 64x64 f4 tile
        int row  = flat >> 6;
        int c4   = flat & 63;
        int gr   = r0 + row; if (gr >= NB_N) gr = 0;      // clamp tail
        float4 v = ((const float4*)(A + (size_t)gr * DD))[c4];
        ushort4 b;
        b.x = f2bf(v.x); b.y = f2bf(v.y); b.z = f2bf(v.z); b.w = f2bf(v.w);
        *(ushort4*)&As[row * 264 + c4 * 4] = b;
    }
    __syncthreads();

    const int lane = t & 63;
    const int wv   = t >> 6;
    const int lr   = lane & 15;
    const int lk   = (lane >> 4) * 8;

    f32x4 acc[4][4];
#pragma unroll
    for (int m = 0; m < 4; m++)
#pragma unroll
        for (int n = 0; n < 4; n++) acc[m][n] = (f32x4){0.f, 0.f, 0.f, 0.f};

#pragma unroll
    for (int ks = 0; ks < 8; ks++) {
        const int k0 = ks * 32;
        bf8 af[4], bb[4];
#pragma unroll
        for (int m = 0; m < 4; m++)
            af[m] = *(const bf8*)&As[(m * 16 + lr) * 264 + k0 + lk];
#pragma unroll
        for (int n = 0; n < 4; n++) {
            int col = wv * 64 + n * 16 + lr;
            bb[n] = *(const bf8*)&Wt[(size_t)col * DD + k0 + lk];
        }
#pragma unroll
        for (int m = 0; m < 4; m++)
#pragma unroll
            for (int n = 0; n < 4; n++)
                acc[m][n] = __builtin_amdgcn_mfma_f32_16x16x32_bf16(
                    af[m], bb[n], acc[m][n], 0, 0, 0);
    }

    float abv[4];
#pragma unroll
    for (int n = 0; n < 4; n++) abv[n] = a_bot[wv * 64 + n * 16 + lr];

    float part[4][4];                        // [m][r] row-dot partials
#pragma unroll
    for (int m = 0; m < 4; m++)
#pragma unroll
        for (int r = 0; r < 4; r++) part[m][r] = 0.f;

#pragma unroll
    for (int m = 0; m < 4; m++)
#pragma unroll
        for (int n = 0; n < 4; n++) {
            int   col = wv * 64 + n * 16 + lr;
            float bv  = bias[col];
#pragma unroll
            for (int r = 0; r < 4; r++) {
                int   rowg = r0 + m * 16 + (lane >> 4) * 4 + r;  // C: col=lane&15, row=(lane>>4)*4+r
                float v    = acc[m][n][r] + bv;
                if (rowg < NB_N) C[(size_t)rowg * DD + col] = f2bf(v);
                part[m][r] = fmaf(v, abv[n], part[m][r]);
            }
        }

    // reduce partials over the 16-lane col group (lr bits)
#pragma unroll
    for (int m = 0; m < 4; m++)
#pragma unroll
        for (int r = 0; r < 4; r++) {
#pragma unroll
            for (int off = 1; off < 16; off <<= 1)
                part[m][r] += __shfl_xor(part[m][r], off, 64);
        }
    if (lr == 0) {
#pragma unroll
        for (int m = 0; m < 4; m++)
#pragma unroll
            for (int r = 0; r < 4; r++)
                sdot[wv][m * 16 + (lane >> 4) * 4 + r] = part[m][r];
    }
    __syncthreads();
    if (t < 64) {
        int rowg = r0 + t;
        if (rowg < NB_N)
            s_b[rowg] = sdot[0][t] + sdot[1][t] + sdot[2][t] + sdot[3][t];
    }
}

// ---------------- row-dot fp32: s_a[i] = dot(fa[i,:], a_top) ----------------
__global__ __launch_bounds__(256) void rowdot(const float* __restrict__ M,
    const float* __restrict__ v, float* __restrict__ out, int nrows)
{
    const int lane = threadIdx.x & 63;
    const int row  = blockIdx.x * 4 + (threadIdx.x >> 6);
    if (row >= nrows) return;
    float4 av = ((const float4*)(M + (size_t)row * DD))[lane];
    float4 bv = ((const float4*)v)[lane];
    float  s  = av.x * bv.x + av.y * bv.y + av.z * bv.z + av.w * bv.w;
#pragma unroll
    for (int off = 32; off; off >>= 1) s += __shfl_down(s, off, 64);
    if (lane == 0) out[row] = s;
}

// ---------------- row_start[r] = first e with esrc[e] >= r (esrc sorted) ----------------
__global__ void rowstart_k(const int* __restrict__ esrc, int* __restrict__ row_start)
{
    int e = blockIdx.x * 256 + threadIdx.x;
    if (e >= NE_N) return;
    int s    = esrc[e];
    int prev = (e == 0) ? -1 : esrc[e - 1];
    for (int r = prev + 1; r <= s; r++) row_start[r] = e;
    if (e == NE_N - 1)
        for (int r = s + 1; r <= NA_N; r++) row_start[r] = NE_N;
}

// ---------------- per-edge score: pairs[e] = (exp(elu(sa[src]+sb[dst])), dst) ----------------
__global__ __launch_bounds__(256) void score_k(
    const int* __restrict__ esrc, const int* __restrict__ edst,
    const float* __restrict__ sa, const float* __restrict__ sb,
    float2* __restrict__ pairs)
{
    int e = blockIdx.x * 256 + threadIdx.x;
    if (e >= NE_N) return;
    int   src = esrc[e], dst = edst[e];
    float lg  = sa[src] + sb[dst];
    float el  = lg > 0.f ? lg : 0.1f * expm1f(lg);
    pairs[e]  = make_float2(expf(el), __int_as_float(dst));
}

// ---------------- edge aggregation: wave per source row, half-wave per edge ----------------
// Lanes 0-31 process edge e, lanes 32-63 edge e+1; each lane gathers ushort8
// (16 B, 32 lanes = full 512 B row). Combine halves via shfl_xor(32). Fused
// normalize + store.
__global__ __launch_bounds__(256) void edge_agg3(
    const float2* __restrict__ pairs, const int* __restrict__ row_start,
    const ushort* __restrict__ emb, float* __restrict__ out)
{
    const int lane = threadIdx.x & 63;
    const int a    = blockIdx.x * 4 + (threadIdx.x >> 6);
    if (a >= NA_N) return;

    const int h  = lane >> 5;
    const int c0 = (lane & 31) * 8;
    const int beg = row_start[a], end = row_start[a + 1];

    float acc0 = 0.f, acc1 = 0.f, acc2 = 0.f, acc3 = 0.f;
    float acc4 = 0.f, acc5 = 0.f, acc6 = 0.f, acc7 = 0.f;
    float rs   = 0.f;

    for (int e = beg; e < end; e += 2) {
        const int ee = e + h;
        float s  = 0.f;
        int   dd = 0;
        if (ee < end) {
            float2 pr = pairs[ee];               // broadcast within half-wave
            s  = pr.x;
            dd = __float_as_int(pr.y);
        }
        u16x8 u = *(const u16x8*)(emb + (size_t)dd * DD + c0);
        acc0 = fmaf(s, bf2f(u[0]), acc0);
        acc1 = fmaf(s, bf2f(u[1]), acc1);
        acc2 = fmaf(s, bf2f(u[2]), acc2);
        acc3 = fmaf(s, bf2f(u[3]), acc3);
        acc4 = fmaf(s, bf2f(u[4]), acc4);
        acc5 = fmaf(s, bf2f(u[5]), acc5);
        acc6 = fmaf(s, bf2f(u[6]), acc6);
        acc7 = fmaf(s, bf2f(u[7]), acc7);
        rs += s;
    }

    // combine the two half-wave partial sums
    acc0 += __shfl_xor(acc0, 32, 64);  acc1 += __shfl_xor(acc1, 32, 64);
    acc2 += __shfl_xor(acc2, 32, 64);  acc3 += __shfl_xor(acc3, 32, 64);
    acc4 += __shfl_xor(acc4, 32, 64);  acc5 += __shfl_xor(acc5, 32, 64);
    acc6 += __shfl_xor(acc6, 32, 64);  acc7 += __shfl_xor(acc7, 32, 64);
    rs   += __shfl_xor(rs, 32, 64);

    const float inv = (rs == 0.f) ? 1.f : (1.f / rs);
    float4 o;                                   // static select, no runtime indexing
    o.x = (h ? acc4 : acc0) * inv;
    o.y = (h ? acc5 : acc1) * inv;
    o.z = (h ? acc6 : acc2) * inv;
    o.w = (h ? acc7 : acc3) * inv;
    *(float4*)(out + (size_t)a * DD + c0 + h * 4) = o;
}

extern "C" void kernel_launch(void* const* d_in, const int* in_sizes, int n_in,
                              void* d_out, int out_size, void* d_ws, size_t ws_size,
                              hipStream_t stream)
{
    const float* fa   = (const float*)d_in[0];
    const float* fb   = (const float*)d_in[1];
    const float* W    = (const float*)d_in[2];
    const float* bias = (const float*)d_in[3];
    const float* avec = (const float*)d_in[4];
    const int*   esrc = (const int*)d_in[5];
    const int*   edst = (const int*)d_in[6];
    float*       out  = (float*)d_out;

    char*   ws        = (char*)d_ws;
    ushort* emb_b     = (ushort*)ws;                                   // 25.6 MB
    float2* pairs     = (float2*)(ws + (size_t)NB_N * DD * 2);         // 6.4 MB
    float*  s_a       = (float*)(pairs + NE_N);                        // NA
    float*  s_b       = s_a + NA_N;                                    // NB
    int*    row_start = (int*)(s_b + NB_N);                            // NA+1
    ushort* Wt        = (ushort*)(row_start + NA_N + 2);               // 128 KB

    wt_cast  <<<16, 256, 0, stream>>>(W, Wt);
    gemm_mfma<<<(NB_N + 63) / 64, 256, 0, stream>>>(fb, Wt, bias, avec + DD,
                                                    emb_b, s_b);
    rowdot   <<<(NA_N + 3) / 4, 256, 0, stream>>>(fa, avec, s_a, NA_N);
    rowstart_k<<<(NE_N + 255) / 256, 256, 0, stream>>>(esrc, row_start);
    score_k  <<<(NE_N + 255) / 256, 256, 0, stream>>>(esrc, edst, s_a, s_b, pairs);
    edge_agg3<<<(NA_N + 3) / 4, 256, 0, stream>>>(pairs, row_start, emb_b, out);
}

// Round 5
// 112.298 us; speedup vs baseline: 3.7830x; 1.1279x over previous
//
#include <hip/hip_runtime.h>
#include <cstdint>

#define NA_N 50000
#define NB_N 50000
#define NE_N 800000
#define DD 256

using bf8   = __attribute__((ext_vector_type(8))) short;   // 8 bf16 = 4 VGPR
using f32x4 = __attribute__((ext_vector_type(4))) float;
using u16x8 = __attribute__((ext_vector_type(8))) ushort;

__device__ __forceinline__ ushort f2bf(float f) {
    uint u = __float_as_uint(f);
    uint r = (u + 0x7fffu + ((u >> 16) & 1u)) >> 16;       // RNE
    return (ushort)r;
}
__device__ __forceinline__ float bf2f(ushort u) {
    return __uint_as_float(((uint)u) << 16);
}

// ---------------- W transpose+cast: Wt[n][k] = bf16(W[k][n]) ----------------
__global__ __launch_bounds__(256) void wt_cast(const float* __restrict__ W,
                                               ushort* __restrict__ Wt)
{
    __shared__ float T[64][65];
    const int bi = blockIdx.x & 3;        // k tile
    const int bj = blockIdx.x >> 2;       // n tile
    const int lane = threadIdx.x & 63, w = threadIdx.x >> 6;
    for (int i = w; i < 64; i += 4)
        T[i][lane] = W[(size_t)(bi * 64 + i) * DD + bj * 64 + lane];
    __syncthreads();
    for (int i = w; i < 64; i += 4)
        Wt[(size_t)(bj * 64 + i) * DD + bi * 64 + lane] = f2bf(T[lane][i]);
}

// ------- GEMM: emb_b[NB,256](bf16) = bf16(fb) @ W + bias ; fused s_b = emb @ a_bot -------
__global__ __launch_bounds__(256) void gemm_mfma(
    const float* __restrict__ A, const ushort* __restrict__ Wt,
    const float* __restrict__ bias, const float* __restrict__ a_bot,
    ushort* __restrict__ C, float* __restrict__ s_b)
{
    __shared__ ushort As[64 * 264];
    __shared__ float  sdot[4][64];
    const int t  = threadIdx.x;
    const int r0 = blockIdx.x * 64;

#pragma unroll
    for (int i = 0; i < 16; i++) {
        int flat = i * 256 + t;
        int row  = flat >> 6;
        int c4   = flat & 63;
        int gr   = r0 + row; if (gr >= NB_N) gr = 0;      // clamp tail
        float4 v = ((const float4*)(A + (size_t)gr * DD))[c4];
        ushort4 b;
        b.x = f2bf(v.x); b.y = f2bf(v.y); b.z = f2bf(v.z); b.w = f2bf(v.w);
        *(ushort4*)&As[row * 264 + c4 * 4] = b;
    }
    __syncthreads();

    const int lane = t & 63;
    const int wv   = t >> 6;
    const int lr   = lane & 15;
    const int lk   = (lane >> 4) * 8;

    f32x4 acc[4][4];
#pragma unroll
    for (int m = 0; m < 4; m++)
#pragma unroll
        for (int n = 0; n < 4; n++) acc[m][n] = (f32x4){0.f, 0.f, 0.f, 0.f};

#pragma unroll
    for (int ks = 0; ks < 8; ks++) {
        const int k0 = ks * 32;
        bf8 af[4], bb[4];
#pragma unroll
        for (int m = 0; m < 4; m++)
            af[m] = *(const bf8*)&As[(m * 16 + lr) * 264 + k0 + lk];
#pragma unroll
        for (int n = 0; n < 4; n++) {
            int col = wv * 64 + n * 16 + lr;
            bb[n] = *(const bf8*)&Wt[(size_t)col * DD + k0 + lk];
        }
#pragma unroll
        for (int m = 0; m < 4; m++)
#pragma unroll
            for (int n = 0; n < 4; n++)
                acc[m][n] = __builtin_amdgcn_mfma_f32_16x16x32_bf16(
                    af[m], bb[n], acc[m][n], 0, 0, 0);
    }

    float abv[4];
#pragma unroll
    for (int n = 0; n < 4; n++) abv[n] = a_bot[wv * 64 + n * 16 + lr];

    float part[4][4];
#pragma unroll
    for (int m = 0; m < 4; m++)
#pragma unroll
        for (int r = 0; r < 4; r++) part[m][r] = 0.f;

#pragma unroll
    for (int m = 0; m < 4; m++)
#pragma unroll
        for (int n = 0; n < 4; n++) {
            int   col = wv * 64 + n * 16 + lr;
            float bv  = bias[col];
#pragma unroll
            for (int r = 0; r < 4; r++) {
                int   rowg = r0 + m * 16 + (lane >> 4) * 4 + r;  // C: col=lane&15, row=(lane>>4)*4+r
                float v    = acc[m][n][r] + bv;
                if (rowg < NB_N) C[(size_t)rowg * DD + col] = f2bf(v);
                part[m][r] = fmaf(v, abv[n], part[m][r]);
            }
        }

#pragma unroll
    for (int m = 0; m < 4; m++)
#pragma unroll
        for (int r = 0; r < 4; r++) {
#pragma unroll
            for (int off = 1; off < 16; off <<= 1)
                part[m][r] += __shfl_xor(part[m][r], off, 64);
        }
    if (lr == 0) {
#pragma unroll
        for (int m = 0; m < 4; m++)
#pragma unroll
            for (int r = 0; r < 4; r++)
                sdot[wv][m * 16 + (lane >> 4) * 4 + r] = part[m][r];
    }
    __syncthreads();
    if (t < 64) {
        int rowg = r0 + t;
        if (rowg < NB_N)
            s_b[rowg] = sdot[0][t] + sdot[1][t] + sdot[2][t] + sdot[3][t];
    }
}

// ---------------- row_start[r] = first e with esrc[e] >= r (esrc sorted) ----------------
__global__ void rowstart_k(const int* __restrict__ esrc, int* __restrict__ row_start)
{
    int e = blockIdx.x * 256 + threadIdx.x;
    if (e >= NE_N) return;
    int s    = esrc[e];
    int prev = (e == 0) ? -1 : esrc[e - 1];
    for (int r = prev + 1; r <= s; r++) row_start[r] = e;
    if (e == NE_N - 1)
        for (int r = s + 1; r <= NA_N; r++) row_start[r] = NE_N;
}

// -------- edge aggregation: wave/row, quarter-wave/edge, fused sa-dot + score + norm --------
// Each wave: (1) sa = dot(fa[a,:], a_top) via 64-lane xor-reduce; (2) 4 edges per
// iter, 16-lane group per edge, each lane 2x16B bf16 loads (full 512 B row, 2
// outstanding loads/lane); score computed inline (2x v_exp); (3) xor-combine the
// 4 groups, normalize, lanes 0-15 write the 1 KB output row.
__global__ __launch_bounds__(256) void edge_agg4(
    const int* __restrict__ edst, const int* __restrict__ row_start,
    const float* __restrict__ fa, const float* __restrict__ a_top,
    const float* __restrict__ sb, const ushort* __restrict__ emb,
    float* __restrict__ out)
{
    const int lane = threadIdx.x & 63;
    const int a    = blockIdx.x * 4 + (threadIdx.x >> 6);
    if (a >= NA_N) return;

    // fused s_a: dot(fa[a,:], a_top)
    float4 av = ((const float4*)(fa + (size_t)a * DD))[lane];
    float4 tv = ((const float4*)a_top)[lane];
    float  sa_a = av.x * tv.x + av.y * tv.y + av.z * tv.z + av.w * tv.w;
#pragma unroll
    for (int off = 1; off < 64; off <<= 1) sa_a += __shfl_xor(sa_a, off, 64);

    const int g = lane >> 4;          // quarter-wave group: edge slot
    const int c = lane & 15;          // 16-col block within row
    const int beg = row_start[a], end = row_start[a + 1];

    float accA[8], accB[8];
#pragma unroll
    for (int j = 0; j < 8; j++) { accA[j] = 0.f; accB[j] = 0.f; }
    float rs = 0.f;

    for (int e = beg; e < end; e += 4) {
        const int ee = e + g;
        if (ee < end) {
            int   dd = edst[ee];
            float lg = sa_a + sb[dd];
            float el = lg > 0.f ? lg : 0.1f * (__expf(lg) - 1.f);
            float s  = __expf(el);
            const ushort* rp = emb + (size_t)dd * DD + c * 16;
            u16x8 u0 = *(const u16x8*)rp;
            u16x8 u1 = *(const u16x8*)(rp + 8);
#pragma unroll
            for (int j = 0; j < 8; j++) {
                accA[j] = fmaf(s, bf2f(u0[j]), accA[j]);
                accB[j] = fmaf(s, bf2f(u1[j]), accB[j]);
            }
            rs += s;
        }
    }

    // combine the 4 quarter-wave partials (xor over group bits 16,32)
#pragma unroll
    for (int j = 0; j < 8; j++) {
        accA[j] += __shfl_xor(accA[j], 16, 64);
        accA[j] += __shfl_xor(accA[j], 32, 64);
        accB[j] += __shfl_xor(accB[j], 16, 64);
        accB[j] += __shfl_xor(accB[j], 32, 64);
    }
    rs += __shfl_xor(rs, 16, 64);
    rs += __shfl_xor(rs, 32, 64);

    if (g == 0) {                      // lanes 0-15 write cols c*16..c*16+15
        const float inv = (rs == 0.f) ? 1.f : (1.f / rs);
        float* op = out + (size_t)a * DD + c * 16;
        float4 o0 = { accA[0] * inv, accA[1] * inv, accA[2] * inv, accA[3] * inv };
        float4 o1 = { accA[4] * inv, accA[5] * inv, accA[6] * inv, accA[7] * inv };
        float4 o2 = { accB[0] * inv, accB[1] * inv, accB[2] * inv, accB[3] * inv };
        float4 o3 = { accB[4] * inv, accB[5] * inv, accB[6] * inv, accB[7] * inv };
        *(float4*)(op + 0)  = o0;
        *(float4*)(op + 4)  = o1;
        *(float4*)(op + 8)  = o2;
        *(float4*)(op + 12) = o3;
    }
}

extern "C" void kernel_launch(void* const* d_in, const int* in_sizes, int n_in,
                              void* d_out, int out_size, void* d_ws, size_t ws_size,
                              hipStream_t stream)
{
    const float* fa   = (const float*)d_in[0];
    const float* fb   = (const float*)d_in[1];
    const float* W    = (const float*)d_in[2];
    const float* bias = (const float*)d_in[3];
    const float* avec = (const float*)d_in[4];
    const int*   esrc = (const int*)d_in[5];
    const int*   edst = (const int*)d_in[6];
    float*       out  = (float*)d_out;

    char*   ws        = (char*)d_ws;
    ushort* emb_b     = (ushort*)ws;                               // 25.6 MB
    float*  s_b       = (float*)(ws + (size_t)NB_N * DD * 2);      // NB
    int*    row_start = (int*)(s_b + NB_N);                        // NA+1
    ushort* Wt        = (ushort*)(row_start + NA_N + 2);           // 128 KB

    wt_cast   <<<16, 256, 0, stream>>>(W, Wt);
    gemm_mfma <<<(NB_N + 63) / 64, 256, 0, stream>>>(fb, Wt, bias, avec + DD,
                                                     emb_b, s_b);
    rowstart_k<<<(NE_N + 255) / 256, 256, 0, stream>>>(esrc, row_start);
    edge_agg4 <<<(NA_N + 3) / 4, 256, 0, stream>>>(edst, row_start, fa, avec,
                                                   s_b, emb_b, out);
}

// Round 6
// 109.286 us; speedup vs baseline: 3.8873x; 1.0276x over previous
//
#include <hip/hip_runtime.h>
#include <cstdint>

#define NA_N 50000
#define NB_N 50000
#define NE_N 800000
#define DD 256

using bf8   = __attribute__((ext_vector_type(8))) short;   // 8 bf16 = 4 VGPR
using f32x4 = __attribute__((ext_vector_type(4))) float;
using u16x8 = __attribute__((ext_vector_type(8))) ushort;

__device__ __forceinline__ ushort f2bf(float f) {
    uint u = __float_as_uint(f);
    uint r = (u + 0x7fffu + ((u >> 16) & 1u)) >> 16;       // RNE
    return (ushort)r;
}
__device__ __forceinline__ float bf2f(ushort u) {
    return __uint_as_float(((uint)u) << 16);
}

// ------- prep: blocks 0-15 transpose+cast W -> Wt[n][k] (bf16); rest build row_start -------
__global__ __launch_bounds__(256) void prep_k(const float* __restrict__ W,
    ushort* __restrict__ Wt, const int* __restrict__ esrc,
    int* __restrict__ row_start)
{
    if (blockIdx.x < 16) {
        __shared__ float T[64][65];
        const int bi = blockIdx.x & 3;        // k tile
        const int bj = blockIdx.x >> 2;       // n tile
        const int lane = threadIdx.x & 63, w = threadIdx.x >> 6;
        for (int i = w; i < 64; i += 4)
            T[i][lane] = W[(size_t)(bi * 64 + i) * DD + bj * 64 + lane];
        __syncthreads();
        for (int i = w; i < 64; i += 4)
            Wt[(size_t)(bj * 64 + i) * DD + bi * 64 + lane] = f2bf(T[lane][i]);
    } else {
        int e = (blockIdx.x - 16) * 256 + threadIdx.x;
        if (e >= NE_N) return;
        int s    = esrc[e];
        int prev = (e == 0) ? -1 : esrc[e - 1];
        for (int r = prev + 1; r <= s; r++) row_start[r] = e;
        if (e == NE_N - 1)
            for (int r = s + 1; r <= NA_N; r++) row_start[r] = NE_N;
    }
}

// ------- GEMM: emb_b[NB,256](bf16) = bf16(fb) @ W + bias ; fused s_b = emb @ a_bot -------
__global__ __launch_bounds__(256) void gemm_mfma(
    const float* __restrict__ A, const ushort* __restrict__ Wt,
    const float* __restrict__ bias, const float* __restrict__ a_bot,
    ushort* __restrict__ C, float* __restrict__ s_b)
{
    __shared__ ushort As[64 * 264];
    __shared__ float  sdot[4][64];
    const int t  = threadIdx.x;
    const int r0 = blockIdx.x * 64;

#pragma unroll
    for (int i = 0; i < 16; i++) {
        int flat = i * 256 + t;
        int row  = flat >> 6;
        int c4   = flat & 63;
        int gr   = r0 + row; if (gr >= NB_N) gr = 0;      // clamp tail
        float4 v = ((const float4*)(A + (size_t)gr * DD))[c4];
        ushort4 b;
        b.x = f2bf(v.x); b.y = f2bf(v.y); b.z = f2bf(v.z); b.w = f2bf(v.w);
        *(ushort4*)&As[row * 264 + c4 * 4] = b;
    }
    __syncthreads();

    const int lane = t & 63;
    const int wv   = t >> 6;
    const int lr   = lane & 15;
    const int lk   = (lane >> 4) * 8;

    f32x4 acc[4][4];
#pragma unroll
    for (int m = 0; m < 4; m++)
#pragma unroll
        for (int n = 0; n < 4; n++) acc[m][n] = (f32x4){0.f, 0.f, 0.f, 0.f};

#pragma unroll
    for (int ks = 0; ks < 8; ks++) {
        const int k0 = ks * 32;
        bf8 af[4], bb[4];
#pragma unroll
        for (int m = 0; m < 4; m++)
            af[m] = *(const bf8*)&As[(m * 16 + lr) * 264 + k0 + lk];
#pragma unroll
        for (int n = 0; n < 4; n++) {
            int col = wv * 64 + n * 16 + lr;
            bb[n] = *(const bf8*)&Wt[(size_t)col * DD + k0 + lk];
        }
#pragma unroll
        for (int m = 0; m < 4; m++)
#pragma unroll
            for (int n = 0; n < 4; n++)
                acc[m][n] = __builtin_amdgcn_mfma_f32_16x16x32_bf16(
                    af[m], bb[n], acc[m][n], 0, 0, 0);
    }

    float abv[4];
#pragma unroll
    for (int n = 0; n < 4; n++) abv[n] = a_bot[wv * 64 + n * 16 + lr];

    float part[4][4];
#pragma unroll
    for (int m = 0; m < 4; m++)
#pragma unroll
        for (int r = 0; r < 4; r++) part[m][r] = 0.f;

#pragma unroll
    for (int m = 0; m < 4; m++)
#pragma unroll
        for (int n = 0; n < 4; n++) {
            int   col = wv * 64 + n * 16 + lr;
            float bv  = bias[col];
#pragma unroll
            for (int r = 0; r < 4; r++) {
                int   rowg = r0 + m * 16 + (lane >> 4) * 4 + r;  // C: col=lane&15, row=(lane>>4)*4+r
                float v    = acc[m][n][r] + bv;
                if (rowg < NB_N) C[(size_t)rowg * DD + col] = f2bf(v);
                part[m][r] = fmaf(v, abv[n], part[m][r]);
            }
        }

#pragma unroll
    for (int m = 0; m < 4; m++)
#pragma unroll
        for (int r = 0; r < 4; r++) {
#pragma unroll
            for (int off = 1; off < 16; off <<= 1)
                part[m][r] += __shfl_xor(part[m][r], off, 64);
        }
    if (lr == 0) {
#pragma unroll
        for (int m = 0; m < 4; m++)
#pragma unroll
            for (int r = 0; r < 4; r++)
                sdot[wv][m * 16 + (lane >> 4) * 4 + r] = part[m][r];
    }
    __syncthreads();
    if (t < 64) {
        int rowg = r0 + t;
        if (rowg < NB_N)
            s_b[rowg] = sdot[0][t] + sdot[1][t] + sdot[2][t] + sdot[3][t];
    }
}

// -------- edge aggregation: wave/row, quarter-wave handles 2 edges/iter --------
// 8 edges in flight per wave-iter; each lane holds 4 outstanding 16 B gathers.
// Loads issued unconditionally (dst=0 / score=0 masking) to keep MLP high.
__global__ __launch_bounds__(256) void edge_agg5(
    const int* __restrict__ edst, const int* __restrict__ row_start,
    const float* __restrict__ fa, const float* __restrict__ a_top,
    const float* __restrict__ sb, const ushort* __restrict__ emb,
    float* __restrict__ out)
{
    const int lane = threadIdx.x & 63;
    const int a    = blockIdx.x * 4 + (threadIdx.x >> 6);
    if (a >= NA_N) return;

    // fused s_a: dot(fa[a,:], a_top)
    float4 av = ((const float4*)(fa + (size_t)a * DD))[lane];
    float4 tv = ((const float4*)a_top)[lane];
    float  sa_a = av.x * tv.x + av.y * tv.y + av.z * tv.z + av.w * tv.w;
#pragma unroll
    for (int off = 1; off < 64; off <<= 1) sa_a += __shfl_xor(sa_a, off, 64);

    const int g = lane >> 4;          // quarter-wave group
    const int c = lane & 15;          // 16-col block within row
    const int beg = row_start[a], end = row_start[a + 1];

    float accA[8], accB[8];
#pragma unroll
    for (int j = 0; j < 8; j++) { accA[j] = 0.f; accB[j] = 0.f; }
    float rs = 0.f;

    for (int e = beg; e < end; e += 8) {
        const int  e0 = e + 2 * g;
        const int  e1 = e0 + 1;
        const bool v0 = e0 < end;
        const bool v1 = e1 < end;

        int d0 = 0, d1 = 0;
        if (v0) d0 = edst[e0];
        if (v1) d1 = edst[e1];

        // issue all 4 row-gather loads before the score math
        const ushort* rp0 = emb + (size_t)d0 * DD + c * 16;
        const ushort* rp1 = emb + (size_t)d1 * DD + c * 16;
        u16x8 u0a = *(const u16x8*)rp0;
        u16x8 u0b = *(const u16x8*)(rp0 + 8);
        u16x8 u1a = *(const u16x8*)rp1;
        u16x8 u1b = *(const u16x8*)(rp1 + 8);

        float lg0 = sa_a + sb[d0];
        float lg1 = sa_a + sb[d1];
        float el0 = lg0 > 0.f ? lg0 : 0.1f * (__expf(lg0) - 1.f);
        float el1 = lg1 > 0.f ? lg1 : 0.1f * (__expf(lg1) - 1.f);
        float s0  = v0 ? __expf(el0) : 0.f;
        float s1  = v1 ? __expf(el1) : 0.f;

#pragma unroll
        for (int j = 0; j < 8; j++) {
            accA[j] = fmaf(s0, bf2f(u0a[j]), accA[j]);
            accA[j] = fmaf(s1, bf2f(u1a[j]), accA[j]);
            accB[j] = fmaf(s0, bf2f(u0b[j]), accB[j]);
            accB[j] = fmaf(s1, bf2f(u1b[j]), accB[j]);
        }
        rs += s0 + s1;
    }

    // combine the 4 quarter-wave partials (xor over group bits 16,32)
#pragma unroll
    for (int j = 0; j < 8; j++) {
        accA[j] += __shfl_xor(accA[j], 16, 64);
        accA[j] += __shfl_xor(accA[j], 32, 64);
        accB[j] += __shfl_xor(accB[j], 16, 64);
        accB[j] += __shfl_xor(accB[j], 32, 64);
    }
    rs += __shfl_xor(rs, 16, 64);
    rs += __shfl_xor(rs, 32, 64);

    if (g == 0) {                      // lanes 0-15 write cols c*16..c*16+15
        const float inv = (rs == 0.f) ? 1.f : (1.f / rs);
        float* op = out + (size_t)a * DD + c * 16;
        float4 o0 = { accA[0] * inv, accA[1] * inv, accA[2] * inv, accA[3] * inv };
        float4 o1 = { accA[4] * inv, accA[5] * inv, accA[6] * inv, accA[7] * inv };
        float4 o2 = { accB[0] * inv, accB[1] * inv, accB[2] * inv, accB[3] * inv };
        float4 o3 = { accB[4] * inv, accB[5] * inv, accB[6] * inv, accB[7] * inv };
        *(float4*)(op + 0)  = o0;
        *(float4*)(op + 4)  = o1;
        *(float4*)(op + 8)  = o2;
        *(float4*)(op + 12) = o3;
    }
}

extern "C" void kernel_launch(void* const* d_in, const int* in_sizes, int n_in,
                              void* d_out, int out_size, void* d_ws, size_t ws_size,
                              hipStream_t stream)
{
    const float* fa   = (const float*)d_in[0];
    const float* fb   = (const float*)d_in[1];
    const float* W    = (const float*)d_in[2];
    const float* bias = (const float*)d_in[3];
    const float* avec = (const float*)d_in[4];
    const int*   esrc = (const int*)d_in[5];
    const int*   edst = (const int*)d_in[6];
    float*       out  = (float*)d_out;

    char*   ws        = (char*)d_ws;
    ushort* emb_b     = (ushort*)ws;                               // 25.6 MB
    float*  s_b       = (float*)(ws + (size_t)NB_N * DD * 2);      // NB
    int*    row_start = (int*)(s_b + NB_N);                        // NA+1
    ushort* Wt        = (ushort*)(row_start + NA_N + 2);           // 128 KB

    prep_k   <<<16 + (NE_N + 255) / 256, 256, 0, stream>>>(W, Wt, esrc, row_start);
    gemm_mfma<<<(NB_N + 63) / 64, 256, 0, stream>>>(fb, Wt, bias, avec + DD,
                                                    emb_b, s_b);
    edge_agg5<<<(NA_N + 3) / 4, 256, 0, stream>>>(edst, row_start, fa, avec,
                                                  s_b, emb_b, out);
}

// Round 7
// 108.457 us; speedup vs baseline: 3.9170x; 1.0076x over previous
//
#include <hip/hip_runtime.h>
#include <cstdint>

#define NA_N 50000
#define NB_N 50000
#define NE_N 800000
#define DD 256

using bf8   = __attribute__((ext_vector_type(8))) short;   // 8 bf16 = 4 VGPR
using f32x4 = __attribute__((ext_vector_type(4))) float;
using u16x8 = __attribute__((ext_vector_type(8))) ushort;

__device__ __forceinline__ ushort f2bf(float f) {
    uint u = __float_as_uint(f);
    uint r = (u + 0x7fffu + ((u >> 16) & 1u)) >> 16;       // RNE
    return (ushort)r;
}
__device__ __forceinline__ float bf2f(ushort u) {
    return __uint_as_float(((uint)u) << 16);
}

// ------- prep: blocks 0-15 transpose+cast W -> Wt[n][k] (bf16); rest build row_start -------
__global__ __launch_bounds__(256) void prep_k(const float* __restrict__ W,
    ushort* __restrict__ Wt, const int* __restrict__ esrc,
    int* __restrict__ row_start)
{
    if (blockIdx.x < 16) {
        __shared__ float T[64][65];
        const int bi = blockIdx.x & 3;        // k tile
        const int bj = blockIdx.x >> 2;       // n tile
        const int lane = threadIdx.x & 63, w = threadIdx.x >> 6;
        for (int i = w; i < 64; i += 4)
            T[i][lane] = W[(size_t)(bi * 64 + i) * DD + bj * 64 + lane];
        __syncthreads();
        for (int i = w; i < 64; i += 4)
            Wt[(size_t)(bj * 64 + i) * DD + bi * 64 + lane] = f2bf(T[lane][i]);
    } else {
        int e = (blockIdx.x - 16) * 256 + threadIdx.x;
        if (e >= NE_N) return;
        int s    = esrc[e];
        int prev = (e == 0) ? -1 : esrc[e - 1];
        for (int r = prev + 1; r <= s; r++) row_start[r] = e;
        if (e == NE_N - 1)
            for (int r = s + 1; r <= NA_N; r++) row_start[r] = NE_N;
    }
}

// ------- GEMM: emb_b[NB,256](bf16) = bf16(fb) @ W + bias ; fused s_b = emb @ a_bot -------
__global__ __launch_bounds__(256) void gemm_mfma(
    const float* __restrict__ A, const ushort* __restrict__ Wt,
    const float* __restrict__ bias, const float* __restrict__ a_bot,
    ushort* __restrict__ C, float* __restrict__ s_b)
{
    __shared__ ushort As[64 * 264];
    __shared__ float  sdot[4][64];
    const int t  = threadIdx.x;
    const int r0 = blockIdx.x * 64;

#pragma unroll
    for (int i = 0; i < 16; i++) {
        int flat = i * 256 + t;
        int row  = flat >> 6;
        int c4   = flat & 63;
        int gr   = r0 + row; if (gr >= NB_N) gr = 0;      // clamp tail
        float4 v = ((const float4*)(A + (size_t)gr * DD))[c4];
        ushort4 b;
        b.x = f2bf(v.x); b.y = f2bf(v.y); b.z = f2bf(v.z); b.w = f2bf(v.w);
        *(ushort4*)&As[row * 264 + c4 * 4] = b;
    }
    __syncthreads();

    const int lane = t & 63;
    const int wv   = t >> 6;
    const int lr   = lane & 15;
    const int lk   = (lane >> 4) * 8;

    f32x4 acc[4][4];
#pragma unroll
    for (int m = 0; m < 4; m++)
#pragma unroll
        for (int n = 0; n < 4; n++) acc[m][n] = (f32x4){0.f, 0.f, 0.f, 0.f};

#pragma unroll
    for (int ks = 0; ks < 8; ks++) {
        const int k0 = ks * 32;
        bf8 af[4], bb[4];
#pragma unroll
        for (int m = 0; m < 4; m++)
            af[m] = *(const bf8*)&As[(m * 16 + lr) * 264 + k0 + lk];
#pragma unroll
        for (int n = 0; n < 4; n++) {
            int col = wv * 64 + n * 16 + lr;
            bb[n] = *(const bf8*)&Wt[(size_t)col * DD + k0 + lk];
        }
#pragma unroll
        for (int m = 0; m < 4; m++)
#pragma unroll
            for (int n = 0; n < 4; n++)
                acc[m][n] = __builtin_amdgcn_mfma_f32_16x16x32_bf16(
                    af[m], bb[n], acc[m][n], 0, 0, 0);
    }

    float abv[4];
#pragma unroll
    for (int n = 0; n < 4; n++) abv[n] = a_bot[wv * 64 + n * 16 + lr];

    float part[4][4];
#pragma unroll
    for (int m = 0; m < 4; m++)
#pragma unroll
        for (int r = 0; r < 4; r++) part[m][r] = 0.f;

#pragma unroll
    for (int m = 0; m < 4; m++)
#pragma unroll
        for (int n = 0; n < 4; n++) {
            int   col = wv * 64 + n * 16 + lr;
            float bv  = bias[col];
#pragma unroll
            for (int r = 0; r < 4; r++) {
                int   rowg = r0 + m * 16 + (lane >> 4) * 4 + r;  // C: col=lane&15, row=(lane>>4)*4+r
                float v    = acc[m][n][r] + bv;
                if (rowg < NB_N) C[(size_t)rowg * DD + col] = f2bf(v);
                part[m][r] = fmaf(v, abv[n], part[m][r]);
            }
        }

#pragma unroll
    for (int m = 0; m < 4; m++)
#pragma unroll
        for (int r = 0; r < 4; r++) {
#pragma unroll
            for (int off = 1; off < 16; off <<= 1)
                part[m][r] += __shfl_xor(part[m][r], off, 64);
        }
    if (lr == 0) {
#pragma unroll
        for (int m = 0; m < 4; m++)
#pragma unroll
            for (int r = 0; r < 4; r++)
                sdot[wv][m * 16 + (lane >> 4) * 4 + r] = part[m][r];
    }
    __syncthreads();
    if (t < 64) {
        int rowg = r0 + t;
        if (rowg < NB_N)
            s_b[rowg] = sdot[0][t] + sdot[1][t] + sdot[2][t] + sdot[3][t];
    }
}

// -------- edge aggregation: wave/row, quarter-wave/edge, depth-2 software pipeline --------
// Iter i: issue stage-(i+1) gathers + stage-(i+2) index/sb preloads, THEN consume
// stage-i data -> the FMAs wait with the next stage's loads still in flight
// (vmcnt(N>0)), doubling effective in-flight misses without exceeding 64 VGPR.
__global__ __launch_bounds__(256) void edge_agg6(
    const int* __restrict__ edst, const int* __restrict__ row_start,
    const float* __restrict__ fa, const float* __restrict__ a_top,
    const float* __restrict__ sb, const ushort* __restrict__ emb,
    float* __restrict__ out)
{
    const int lane = threadIdx.x & 63;
    const int a    = blockIdx.x * 4 + (threadIdx.x >> 6);
    if (a >= NA_N) return;

    // fused s_a: dot(fa[a,:], a_top)
    float4 av = ((const float4*)(fa + (size_t)a * DD))[lane];
    float4 tv = ((const float4*)a_top)[lane];
    float  sa_a = av.x * tv.x + av.y * tv.y + av.z * tv.z + av.w * tv.w;
#pragma unroll
    for (int off = 1; off < 64; off <<= 1) sa_a += __shfl_xor(sa_a, off, 64);

    const int g = lane >> 4;          // quarter-wave group: one edge per stage
    const int c = lane & 15;          // 16-col block within row
    const int beg = row_start[a], end = row_start[a + 1];

    float accA[8], accB[8];
#pragma unroll
    for (int j = 0; j < 8; j++) { accA[j] = 0.f; accB[j] = 0.f; }
    float rs = 0.f;

    if (beg < end) {
        const int last = end - 1;

        int   pc  = beg + g;                      // current-stage position
        int   pn  = pc + 4;                       // next-stage position
        int   dc  = edst[min(pc, last)];
        int   dn  = edst[min(pn, last)];
        float sbc = sb[dc];
        float sbn = sb[dn];
        const ushort* rc = emb + (size_t)dc * DD + c * 16;
        u16x8 ua = *(const u16x8*)rc;             // stage-0 gathers in flight
        u16x8 ub = *(const u16x8*)(rc + 8);

#pragma unroll 2
        for (int e = beg; e < end; e += 4) {
            // issue next-stage gathers (independent of current consumption)
            const ushort* rn = emb + (size_t)dn * DD + c * 16;
            u16x8 na = *(const u16x8*)rn;
            u16x8 nb = *(const u16x8*)(rn + 8);
            // preload stage+2 index & sb
            int   p2  = pn + 4;
            int   d2  = edst[min(p2, last)];
            float sb2 = sb[d2];

            // score for current stage (redundant across the 16-lane group; cheap)
            float lg = sa_a + sbc;
            float el = lg > 0.f ? lg : 0.1f * (__expf(lg) - 1.f);
            float s  = (pc < end) ? __expf(el) : 0.f;

            // consume current gathers (waits only on ua/ub — older loads)
#pragma unroll
            for (int j = 0; j < 8; j++) {
                accA[j] = fmaf(s, bf2f(ua[j]), accA[j]);
                accB[j] = fmaf(s, bf2f(ub[j]), accB[j]);
            }
            rs += s;

            // rotate pipeline (pure renaming after unroll)
            pc = pn;  dc = dn;  sbc = sbn;
            ua = na;  ub = nb;
            pn = p2;  dn = d2;  sbn = sb2;
        }
    }

    // combine the 4 quarter-wave partials (xor over group bits 16,32)
#pragma unroll
    for (int j = 0; j < 8; j++) {
        accA[j] += __shfl_xor(accA[j], 16, 64);
        accA[j] += __shfl_xor(accA[j], 32, 64);
        accB[j] += __shfl_xor(accB[j], 16, 64);
        accB[j] += __shfl_xor(accB[j], 32, 64);
    }
    rs += __shfl_xor(rs, 16, 64);
    rs += __shfl_xor(rs, 32, 64);

    if (g == 0) {                      // lanes 0-15 write cols c*16..c*16+15
        const float inv = (rs == 0.f) ? 1.f : (1.f / rs);
        float* op = out + (size_t)a * DD + c * 16;
        float4 o0 = { accA[0] * inv, accA[1] * inv, accA[2] * inv, accA[3] * inv };
        float4 o1 = { accA[4] * inv, accA[5] * inv, accA[6] * inv, accA[7] * inv };
        float4 o2 = { accB[0] * inv, accB[1] * inv, accB[2] * inv, accB[3] * inv };
        float4 o3 = { accB[4] * inv, accB[5] * inv, accB[6] * inv, accB[7] * inv };
        *(float4*)(op + 0)  = o0;
        *(float4*)(op + 4)  = o1;
        *(float4*)(op + 8)  = o2;
        *(float4*)(op + 12) = o3;
    }
}

extern "C" void kernel_launch(void* const* d_in, const int* in_sizes, int n_in,
                              void* d_out, int out_size, void* d_ws, size_t ws_size,
                              hipStream_t stream)
{
    const float* fa   = (const float*)d_in[0];
    const float* fb   = (const float*)d_in[1];
    const float* W    = (const float*)d_in[2];
    const float* bias = (const float*)d_in[3];
    const float* avec = (const float*)d_in[4];
    const int*   esrc = (const int*)d_in[5];
    const int*   edst = (const int*)d_in[6];
    float*       out  = (float*)d_out;

    char*   ws        = (char*)d_ws;
    ushort* emb_b     = (ushort*)ws;                               // 25.6 MB
    float*  s_b       = (float*)(ws + (size_t)NB_N * DD * 2);      // NB
    int*    row_start = (int*)(s_b + NB_N);                        // NA+1
    ushort* Wt        = (ushort*)(row_start + NA_N + 2);           // 128 KB

    prep_k   <<<16 + (NE_N + 255) / 256, 256, 0, stream>>>(W, Wt, esrc, row_start);
    gemm_mfma<<<(NB_N + 63) / 64, 256, 0, stream>>>(fb, Wt, bias, avec + DD,
                                                    emb_b, s_b);
    edge_agg6<<<(NA_N + 3) / 4, 256, 0, stream>>>(edst, row_start, fa, avec,
                                                  s_b, emb_b, out);
}